// Round 6
// baseline (207.047 us; speedup 1.0000x reference)
//
#include <hip/hip_runtime.h>

// FocalCTCLoss on MI355X — round 6.
// B=256, T=1024, V=128 (BLANK=127), L=64, S=129.
//
// Round-5 post-mortem: producer loads issued after each phase barrier ->
// memory pipeline idle during consumer compute and across barriers (duty
// cycle ~40%) -> effective per-CU HBM BW ~3-4 B/cy instead of 10. Fix:
// register-pipelined producer — hold chunk p in VGPRs, write it to LDS +
// reduce, then issue chunk p+1 loads BEFORE the barrier. __syncthreads's
// vmcnt(0) drain then doubles as the prefetch wait: the fetch of chunk p+1
// overlaps all of phase p. Steady-state phase = max(64KB fetch, consumer).
// Also: exact 64-pair/15-wave distribution (no redundant clamped loads).

#define EPSF 1e-7f

constexpr int Bb  = 256;
constexpr int Tt  = 1024;
constexpr int Vv  = 128;
constexpr int Ll  = 64;
constexpr int CH  = 128;       // timesteps per chunk
constexpr int NCH = Tt / CH;   // 8 chunks
constexpr int PAIRS = CH / 2;  // 64 row-pairs per chunk (1 KB each)

// ---- DPP helpers -----------------------------------------------------------
template <int Ctrl, int RowMask, int BankMask, bool BoundCtrl>
__device__ __forceinline__ float dppf(float x) {
    return __int_as_float(__builtin_amdgcn_update_dpp(
        0, __float_as_int(x), Ctrl, RowMask, BankMask, BoundCtrl));
}

// Wave-64 sum, valid on lane 63 (inputs >= 0; 0-fill is identity).
__device__ __forceinline__ float wave_sum63(float x) {
    x += dppf<0x111, 0xf, 0xf, true>(x);
    x += dppf<0x112, 0xf, 0xf, true>(x);
    x += dppf<0x114, 0xf, 0xf, true>(x);
    x += dppf<0x118, 0xf, 0xf, true>(x);
    x += dppf<0x142, 0xa, 0xf, false>(x);  // row_bcast15 -> rows 1,3
    x += dppf<0x143, 0xc, 0xf, false>(x);  // row_bcast31 -> rows 2,3
    return x;
}

// Half-wave sums: lane 31 = sum(lanes 0..31), lane 63 = sum(lanes 32..63).
__device__ __forceinline__ float half_sum(float x) {
    x += dppf<0x111, 0xf, 0xf, true>(x);
    x += dppf<0x112, 0xf, 0xf, true>(x);
    x += dppf<0x114, 0xf, 0xf, true>(x);
    x += dppf<0x118, 0xf, 0xf, true>(x);
    x += dppf<0x142, 0xa, 0xf, false>(x);
    return x;
}

// Wave-64 max (non-negative inputs), valid on lane 63.
__device__ __forceinline__ float wave_max63(float x) {
    x = fmaxf(x, dppf<0x111, 0xf, 0xf, true>(x));
    x = fmaxf(x, dppf<0x112, 0xf, 0xf, true>(x));
    x = fmaxf(x, dppf<0x114, 0xf, 0xf, true>(x));
    x = fmaxf(x, dppf<0x118, 0xf, 0xf, true>(x));
    x = fmaxf(x, dppf<0x142, 0xa, 0xf, false>(x));
    x = fmaxf(x, dppf<0x143, 0xc, 0xf, false>(x));
    return x;
}

__device__ __forceinline__ float bcast63(float x) {
    return __int_as_float(__builtin_amdgcn_readlane(__float_as_int(x), 63));
}

// ---- fused producer-consumer kernel: one block per batch element -----------
__launch_bounds__(1024, 1)
__global__ void fused_kernel(const int* __restrict__ y_true,
                             const float* __restrict__ y_pred,
                             float* __restrict__ focal_ws) {
    const int b    = blockIdx.x;
    const int lane = threadIdx.x & 63;
    const int wv   = threadIdx.x >> 6;  // 0..15

    const float*  yb  = y_pred + (size_t)b * Tt * Vv;
    const float4* yb4 = (const float4*)yb;

    __shared__ float4 l4buf[2 * CH * (Vv / 4)];  // 128 KB double-buffered tile
    __shared__ float  lblk[2 * CH];              // u[t][127] per step
    __shared__ float  part[30];                  // 15 waves x 2 half partials
    float* lrows = (float*)l4buf;

    // ---- DP state (wave 0; meaningful on lane 63) --------------------------
    float a_even = 0.0f, a_odd = 0.0f, a128 = 0.0f;
    int   eacc = 0;
    float maskf = 0.0f;
    int   lab = 0;

    // ---- producer state (waves 1..15) --------------------------------------
    // Row-pair distribution: waves 0..3 -> 5 pairs, waves 4..14 -> 4 pairs.
    const int w     = wv - 1;                         // 0..14
    const int start = (w < 4) ? 5 * w : 20 + 4 * (w - 4);
    const int cnt   = (w < 4) ? 5 : 4;                // wave-uniform
    const int half  = lane >> 5;                      // 0/1: even/odd row
    float  ll = 0.0f;                                 // lanes 31/63: log sums
    float4 v[5];

    if (wv == 0) {
        lab = y_true[b * Ll + lane];           // label of odd state 2*lane+1
        const int labp = __shfl_up(lab, 1);
        maskf  = (lane == 0 || lab != labp) ? 1.0f : 0.0f;
        a_even = (lane == 0) ? 1.0f : 0.0f;    // pre-t0 init
    } else {
        // prologue: fetch chunk 0 into registers
#pragma unroll
        for (int k = 0; k < 5; ++k)
            if (k < cnt) v[k] = yb4[(start + k) * 64 + lane];
    }

    auto step = [&](float g, float qbl, bool check) {
        const float qe  = g + EPSF;
        const float qb  = qbl + EPSF;
        const float am1 = dppf<0x138, 0xf, 0xf, true>(a_odd);  // alpha[2i-1]
        const float ne   = (a_even + am1) * qb;
        const float no   = (a_odd + a_even + maskf * am1) * qe;
        const float n128 = (a128 + a_odd) * qb;  // lane 63 only
        a_even = ne;
        a_odd  = no;
        a128   = n128;
        if (check) {
            // Values only shrink (q <= 1+eps); rescale on underflow risk only.
            const float m = fmaxf(fmaxf(a_even, a_odd), a128);
            if (__all(m < 0x1p-25f)) {
                float mm = wave_max63(m);
                const float    wmax  = bcast63(mm);            // > 0
                const unsigned e     = __float_as_uint(wmax) >> 23;
                const float    scale = __uint_as_float((254u - e) << 23);
                eacc += (int)e - 127;
                a_even *= scale;
                a_odd  *= scale;
                a128   *= scale;
            }
        }
    };

    for (int p = 0; p <= NCH; ++p) {
        if (wv != 0) {
            if (p < NCH) {
                // ---- publish chunk p from registers; fold row-sum logs ----
                const int bsel  = p & 1;
                const int lbase = bsel * CH * (Vv / 4);
#pragma unroll
                for (int k = 0; k < 5; ++k) {
                    if (k < cnt) {
                        const int rp = start + k;
                        l4buf[lbase + rp * 64 + lane] = v[k];
                        const float s =
                            half_sum(v[k].x + v[k].y + v[k].z + v[k].w);
                        if ((lane & 31) == 31) {
                            // lane 31: row 2rp, lane 63: row 2rp+1;
                            // v.w of these lanes is u[row][127] (blank).
                            lblk[bsel * CH + 2 * rp + half] = v[k].w;
                            ll += __log2f(s + (float)Vv * EPSF);
                        }
                    }
                }
                // ---- issue chunk p+1 loads; they stay in flight through
                // the barrier (its vmcnt(0) drain IS the prefetch wait) ----
                if (p + 1 < NCH) {
                    const int gbase = (p + 1) * CH * (Vv / 4);
#pragma unroll
                    for (int k = 0; k < 5; ++k)
                        if (k < cnt) v[k] = yb4[gbase + (start + k) * 64 + lane];
                }
            } else if ((lane & 31) == 31) {
                part[2 * w + half] = ll;  // p == NCH: publish denom partials
            }
        } else if (p > 0) {
            // ---- consume chunk p-1 from buffer ((p-1)&1) -------------------
            const int bsel = (p - 1) & 1;
            const int cb   = bsel * CH * Vv;
            const int bb   = bsel * CH;
            constexpr int PD = 8;
            float gq[PD], bq[PD];
#pragma unroll
            for (int d = 0; d < PD; ++d) {
                gq[d] = lrows[cb + d * Vv + lab];  // divergent gather
                bq[d] = lblk[bb + d];              // uniform broadcast
            }
            for (int t0 = 0; t0 < CH - PD; t0 += PD) {
#pragma unroll
                for (int j = 0; j < PD; ++j) {
                    const float g = gq[j];
                    const float q = bq[j];
                    const int  tn = t0 + j + PD;
                    gq[j] = lrows[cb + tn * Vv + lab];
                    bq[j] = lblk[bb + tn];
                    step(g, q, (j & 3) == 3);
                }
            }
#pragma unroll
            for (int j = 0; j < PD; ++j) step(gq[j], bq[j], (j & 3) == 3);
        }
        __syncthreads();
    }

    if (wv == 0) {
        float vs = (lane < 30) ? part[lane] : 0.0f;
        vs = wave_sum63(vs);
        if (lane == 63) {
            const float acc_ld = vs;  // sum_t log2(S_t + V*eps)
            const float tot    = fmaxf(a128 + a_odd, 1e-37f);
            const float log2lik = __log2f(tot) + (float)eacc - acc_ld;
            const float ln_lik  = 0.69314718055994530942f * log2lik;
            const float loss    = -ln_lik;
            const float pp      = __expf(ln_lik);
            const float om      = 1.0f - pp;
            focal_ws[b] = 0.25f * om * om * loss;
        }
    }
}

// ---- focal mean -------------------------------------------------------------
__global__ void finalize_kernel(const float* __restrict__ focal_ws,
                                float* __restrict__ out) {
    const int i    = threadIdx.x;  // 256 threads = 4 waves
    const int lane = i & 63;
    const int wv   = i >> 6;

    float f = focal_ws[i];
#pragma unroll
    for (int off = 32; off > 0; off >>= 1) f += __shfl_xor(f, off);

    __shared__ float red[4];
    if (lane == 0) red[wv] = f;
    __syncthreads();
    if (i == 0)
        out[0] = (red[0] + red[1] + red[2] + red[3]) * (1.0f / (float)Bb);
}

extern "C" void kernel_launch(void* const* d_in, const int* in_sizes, int n_in,
                              void* d_out, int out_size, void* d_ws, size_t ws_size,
                              hipStream_t stream) {
    const int*   y_true = (const int*)d_in[0];    // [B, L] int32
    const float* y_pred = (const float*)d_in[1];  // [B, T, V] float32
    float* focal_ws = (float*)d_ws;               // [B]

    fused_kernel<<<Bb, 1024, 0, stream>>>(y_true, y_pred, focal_ws);
    finalize_kernel<<<1, 256, 0, stream>>>(focal_ws, (float*)d_out);
}

// Round 9
// 204.341 us; speedup vs baseline: 1.0132x; 1.0132x over previous
//
#include <hip/hip_runtime.h>

// FocalCTCLoss on MI355X — round 7 experiment, attempt 3.
// (R7/R8 benches died with "MI355X container failed twice" — broker infra.
//  One latent UB fixed this attempt: lblk was read via float4*/ds_read_b128
//  but only guaranteed 4B-aligned as a plain __shared__ float array; now
//  alignas(16). Otherwise bit-identical to R7.)
// B=256, T=1024, V=128 (BLANK=127), L=64, S=129.
//
// Round-6 post-mortem: R6's producer prefetch was neutral (64->69us) ->
// consumer is the limiter. Its 8-deep rotating prefetch kept 16 DS ops
// outstanding — at/over the 4-bit lgkmcnt limit — so the compiler waited
// conservatively and each step paid most of the ~120cy ds_read latency
// (~150cy/step, matching all prior feed paths: R2 global 284, R4 SMEM 222).
//
// Fix (consumer only): group-hoisted LDS reads. Gathers batched 8 at a time
// into ping-pong register buffers (issued ~200cy before first use, <=10 DS
// outstanding -> fine-grained lgkmcnt); blank values read as float4 (1 DS op
// per 4 steps). Per-step DS issue 2 -> 1.25, latency exposure ~0.

#define EPSF 1e-7f

constexpr int Bb  = 256;
constexpr int Tt  = 1024;
constexpr int Vv  = 128;
constexpr int Ll  = 64;
constexpr int CH  = 128;       // timesteps per chunk
constexpr int NCH = Tt / CH;   // 8 chunks
constexpr int PAIRS = CH / 2;  // 64 row-pairs per chunk (1 KB each)

// ---- DPP helpers -----------------------------------------------------------
template <int Ctrl, int RowMask, int BankMask, bool BoundCtrl>
__device__ __forceinline__ float dppf(float x) {
    return __int_as_float(__builtin_amdgcn_update_dpp(
        0, __float_as_int(x), Ctrl, RowMask, BankMask, BoundCtrl));
}

// Wave-64 sum, valid on lane 63 (inputs >= 0; 0-fill is identity).
__device__ __forceinline__ float wave_sum63(float x) {
    x += dppf<0x111, 0xf, 0xf, true>(x);
    x += dppf<0x112, 0xf, 0xf, true>(x);
    x += dppf<0x114, 0xf, 0xf, true>(x);
    x += dppf<0x118, 0xf, 0xf, true>(x);
    x += dppf<0x142, 0xa, 0xf, false>(x);  // row_bcast15 -> rows 1,3
    x += dppf<0x143, 0xc, 0xf, false>(x);  // row_bcast31 -> rows 2,3
    return x;
}

// Half-wave sums: lane 31 = sum(lanes 0..31), lane 63 = sum(lanes 32..63).
__device__ __forceinline__ float half_sum(float x) {
    x += dppf<0x111, 0xf, 0xf, true>(x);
    x += dppf<0x112, 0xf, 0xf, true>(x);
    x += dppf<0x114, 0xf, 0xf, true>(x);
    x += dppf<0x118, 0xf, 0xf, true>(x);
    x += dppf<0x142, 0xa, 0xf, false>(x);
    return x;
}

// Wave-64 max (non-negative inputs), valid on lane 63.
__device__ __forceinline__ float wave_max63(float x) {
    x = fmaxf(x, dppf<0x111, 0xf, 0xf, true>(x));
    x = fmaxf(x, dppf<0x112, 0xf, 0xf, true>(x));
    x = fmaxf(x, dppf<0x114, 0xf, 0xf, true>(x));
    x = fmaxf(x, dppf<0x118, 0xf, 0xf, true>(x));
    x = fmaxf(x, dppf<0x142, 0xa, 0xf, false>(x));
    x = fmaxf(x, dppf<0x143, 0xc, 0xf, false>(x));
    return x;
}

__device__ __forceinline__ float bcast63(float x) {
    return __int_as_float(__builtin_amdgcn_readlane(__float_as_int(x), 63));
}

__device__ __forceinline__ float f4get(const float4& v, int j) {
    switch (j & 3) {
        case 0:  return v.x;
        case 1:  return v.y;
        case 2:  return v.z;
        default: return v.w;
    }
}

// ---- fused producer-consumer kernel: one block per batch element -----------
__launch_bounds__(1024, 1)
__global__ void fused_kernel(const int* __restrict__ y_true,
                             const float* __restrict__ y_pred,
                             float* __restrict__ focal_ws) {
    const int b    = blockIdx.x;
    const int lane = threadIdx.x & 63;
    const int wv   = threadIdx.x >> 6;  // 0..15

    const float*  yb  = y_pred + (size_t)b * Tt * Vv;
    const float4* yb4 = (const float4*)yb;

    __shared__ float4 l4buf[2 * CH * (Vv / 4)];        // 128 KB dbuf tile
    __shared__ alignas(16) float lblk[2 * CH];         // u[t][127] per step
    __shared__ alignas(16) float part[32];             // denom partials
    float* lrows = (float*)l4buf;

    // ---- DP state (wave 0; meaningful on lane 63) --------------------------
    float a_even = 0.0f, a_odd = 0.0f, a128 = 0.0f;
    int   eacc = 0;
    float maskf = 0.0f;
    int   lab = 0;

    // ---- producer state (waves 1..15) --------------------------------------
    // Row-pair distribution: waves 0..3 -> 5 pairs, waves 4..14 -> 4 pairs.
    const int w     = wv - 1;                         // 0..14
    const int start = (w < 4) ? 5 * w : 20 + 4 * (w - 4);
    const int cnt   = (w < 4) ? 5 : 4;                // wave-uniform
    const int half  = lane >> 5;                      // 0/1: even/odd row
    float  ll = 0.0f;                                 // lanes 31/63: log sums
    float4 v[5];

    if (wv == 0) {
        lab = y_true[b * Ll + lane];           // label of odd state 2*lane+1
        const int labp = __shfl_up(lab, 1);
        maskf  = (lane == 0 || lab != labp) ? 1.0f : 0.0f;
        a_even = (lane == 0) ? 1.0f : 0.0f;    // pre-t0 init
    } else {
        // prologue: fetch chunk 0 into registers
#pragma unroll
        for (int k = 0; k < 5; ++k)
            if (k < cnt) v[k] = yb4[(start + k) * 64 + lane];
    }

    auto step = [&](float g, float qbl, bool check) {
        const float qe  = g + EPSF;
        const float qb  = qbl + EPSF;
        const float am1 = dppf<0x138, 0xf, 0xf, true>(a_odd);  // alpha[2i-1]
        const float ne   = (a_even + am1) * qb;
        const float no   = (a_odd + a_even + maskf * am1) * qe;
        const float n128 = (a128 + a_odd) * qb;  // lane 63 only
        a_even = ne;
        a_odd  = no;
        a128   = n128;
        if (check) {
            // Values only shrink (q <= 1+eps); rescale on underflow risk only.
            const float m = fmaxf(fmaxf(a_even, a_odd), a128);
            if (__all(m < 0x1p-25f)) {
                float mm = wave_max63(m);
                const float    wmax  = bcast63(mm);            // > 0
                const unsigned e     = __float_as_uint(wmax) >> 23;
                const float    scale = __uint_as_float((254u - e) << 23);
                eacc += (int)e - 127;
                a_even *= scale;
                a_odd  *= scale;
                a128   *= scale;
            }
        }
    };

    for (int p = 0; p <= NCH; ++p) {
        if (wv != 0) {
            if (p < NCH) {
                // ---- publish chunk p from registers; fold row-sum logs ----
                const int bsel  = p & 1;
                const int lbase = bsel * CH * (Vv / 4);
#pragma unroll
                for (int k = 0; k < 5; ++k) {
                    if (k < cnt) {
                        const int rp = start + k;
                        l4buf[lbase + rp * 64 + lane] = v[k];
                        const float s =
                            half_sum(v[k].x + v[k].y + v[k].z + v[k].w);
                        if ((lane & 31) == 31) {
                            // lane 31: row 2rp, lane 63: row 2rp+1;
                            // v.w of these lanes is u[row][127] (blank).
                            lblk[bsel * CH + 2 * rp + half] = v[k].w;
                            ll += __log2f(s + (float)Vv * EPSF);
                        }
                    }
                }
                // ---- issue chunk p+1 loads; in flight through the barrier -
                if (p + 1 < NCH) {
                    const int gbase = (p + 1) * CH * (Vv / 4);
#pragma unroll
                    for (int k = 0; k < 5; ++k)
                        if (k < cnt) v[k] = yb4[gbase + (start + k) * 64 + lane];
                }
            } else if ((lane & 31) == 31) {
                part[2 * w + half] = ll;  // p == NCH: publish denom partials
            }
        } else if (p > 0) {
            // ---- consume chunk p-1: group-hoisted LDS reads ----------------
            // Groups of 8 timesteps; ping-pong register buffers A/B. A group's
            // 8 gathers + 2 float4 blank reads are issued a full group (~8
            // steps, ~200cy) before first use -> DS latency fully covered,
            // <=10 DS ops outstanding (fine-grained lgkmcnt).
            const int     bsel = (p - 1) & 1;
            const float*  g0   = lrows + bsel * CH * Vv + lab;  // gather base
            const float4* bl   = (const float4*)(lblk + bsel * CH);

            float  A[8], Bv[8];
            float4 bA[2], bB[2];
#pragma unroll
            for (int j = 0; j < 8; ++j) A[j] = g0[j * Vv];  // group 0
            bA[0] = bl[0];
            bA[1] = bl[1];

            for (int k = 0; k < 8; ++k) {       // pairs (2k, 2k+1)
                const int gB = 2 * k + 1;
                const float* gb = g0 + gB * 8 * Vv;         // prefetch 2k+1
#pragma unroll
                for (int j = 0; j < 8; ++j) Bv[j] = gb[j * Vv];
                bB[0] = bl[2 * gB];
                bB[1] = bl[2 * gB + 1];
#pragma unroll
                for (int j = 0; j < 8; ++j)                 // consume 2k
                    step(A[j], f4get(bA[j >> 2], j), (j & 3) == 3);
                if (k + 1 < 8) {                            // prefetch 2k+2
                    const float* ga = g0 + (gB + 1) * 8 * Vv;
#pragma unroll
                    for (int j = 0; j < 8; ++j) A[j] = ga[j * Vv];
                    bA[0] = bl[2 * gB + 2];
                    bA[1] = bl[2 * gB + 3];
                }
#pragma unroll
                for (int j = 0; j < 8; ++j)                 // consume 2k+1
                    step(Bv[j], f4get(bB[j >> 2], j), (j & 3) == 3);
            }
        }
        __syncthreads();
    }

    if (wv == 0) {
        float vs = (lane < 30) ? part[lane] : 0.0f;
        vs = wave_sum63(vs);
        if (lane == 63) {
            const float acc_ld = vs;  // sum_t log2(S_t + V*eps)
            const float tot    = fmaxf(a128 + a_odd, 1e-37f);
            const float log2lik = __log2f(tot) + (float)eacc - acc_ld;
            const float ln_lik  = 0.69314718055994530942f * log2lik;
            const float loss    = -ln_lik;
            const float pp      = __expf(ln_lik);
            const float om      = 1.0f - pp;
            focal_ws[b] = 0.25f * om * om * loss;
        }
    }
}

// ---- focal mean -------------------------------------------------------------
__global__ void finalize_kernel(const float* __restrict__ focal_ws,
                                float* __restrict__ out) {
    const int i    = threadIdx.x;  // 256 threads = 4 waves
    const int lane = i & 63;
    const int wv   = i >> 6;

    float f = focal_ws[i];
#pragma unroll
    for (int off = 32; off > 0; off >>= 1) f += __shfl_xor(f, off);

    __shared__ float red[4];
    if (lane == 0) red[wv] = f;
    __syncthreads();
    if (i == 0)
        out[0] = (red[0] + red[1] + red[2] + red[3]) * (1.0f / (float)Bb);
}

extern "C" void kernel_launch(void* const* d_in, const int* in_sizes, int n_in,
                              void* d_out, int out_size, void* d_ws, size_t ws_size,
                              hipStream_t stream) {
    const int*   y_true = (const int*)d_in[0];    // [B, L] int32
    const float* y_pred = (const float*)d_in[1];  // [B, T, V] float32
    float* focal_ws = (float*)d_ws;               // [B]

    fused_kernel<<<Bb, 1024, 0, stream>>>(y_true, y_pred, focal_ws);
    finalize_kernel<<<1, 256, 0, stream>>>(focal_ws, (float*)d_out);
}